// Round 5
// baseline (685.748 us; speedup 1.0000x reference)
//
#include <hip/hip_runtime.h>

typedef unsigned short U16;
typedef unsigned int U32;
typedef __bf16 bf16;
typedef bf16 bf16x8 __attribute__((ext_vector_type(8)));
typedef U16  u16x8  __attribute__((ext_vector_type(8)));
typedef U16  u16x4  __attribute__((ext_vector_type(4)));
typedef float f32x4 __attribute__((ext_vector_type(4)));

// Exact 3-limb bf16 chop split: a == a1 + a2 + a3 (fp32 24-bit significand
// = 3 x 8-bit bf16 limbs; bf16 exponent range == fp32 so no subnormal loss).
__device__ __forceinline__ void split3(float a, U16& o1, U16& o2, U16& o3) {
    U32 ua = __float_as_uint(a);
    float a1 = __uint_as_float(ua & 0xFFFF0000u);
    float r1 = a - a1;
    U32 u2 = __float_as_uint(r1);
    float a2 = __uint_as_float(u2 & 0xFFFF0000u);
    float r2 = r1 - a2;                     // exact in bf16 (<=8 sig bits left)
    o1 = (U16)(ua >> 16);
    o2 = (U16)(u2 >> 16);
    o3 = (U16)(__float_as_uint(r2) >> 16);
}

__device__ __forceinline__ void split3x8(const float v[8], bf16x8& A1, bf16x8& A2, bf16x8& A3) {
    u16x8 e1, e2, e3;
    #pragma unroll
    for (int j = 0; j < 8; ++j) { U16 a, b, c; split3(v[j], a, b, c); e1[j] = a; e2[j] = b; e3[j] = c; }
    A1 = __builtin_bit_cast(bf16x8, e1);
    A2 = __builtin_bit_cast(bf16x8, e2);
    A3 = __builtin_bit_cast(bf16x8, e3);
}

// ---------------- prep: split w1/w2 into bf16 limb planes in d_ws ----------
// w1L: [3][128 n][128 k] bf16 (k 112..127 zero)  = 98304 B at ws+0
// w2L: [3][32 n][128 k]  bf16                    = 24576 B at ws+98304
__global__ __launch_bounds__(256)
void prep_kernel(const float* __restrict__ w1g, const float* __restrict__ w2g,
                 U16* __restrict__ w1L, U16* __restrict__ w2L)
{
    int tid = blockIdx.x * 256 + threadIdx.x;
    if (tid < 2048) {                       // 128 rows x 16 slots of 8 k
        int n = tid >> 4, k0 = (tid & 15) << 3;
        float v[8];
        #pragma unroll
        for (int j = 0; j < 8; ++j) { int k = k0 + j; v[j] = (k < 112) ? w1g[n * 112 + k] : 0.0f; }
        bf16x8 L1, L2, L3; split3x8(v, L1, L2, L3);
        *(bf16x8*)(w1L + 0 * 16384 + n * 128 + k0) = L1;
        *(bf16x8*)(w1L + 1 * 16384 + n * 128 + k0) = L2;
        *(bf16x8*)(w1L + 2 * 16384 + n * 128 + k0) = L3;
    }
    if (tid < 512) {                        // 32 rows x 16 slots
        int n = tid >> 4, k0 = (tid & 15) << 3;
        float v[8];
        #pragma unroll
        for (int j = 0; j < 8; ++j) v[j] = w2g[n * 128 + k0 + j];
        bf16x8 L1, L2, L3; split3x8(v, L1, L2, L3);
        *(bf16x8*)(w2L + 0 * 4096 + n * 128 + k0) = L1;
        *(bf16x8*)(w2L + 1 * 4096 + n * 128 + k0) = L2;
        *(bf16x8*)(w2L + 2 * 4096 + n * 128 + k0) = L3;
    }
}

// ---------------- barrier macros (NO vmcnt drain — keep loads in flight) ---
#define WBAR() do { asm volatile("s_waitcnt lgkmcnt(0)" ::: "memory"); \
                    __builtin_amdgcn_s_barrier();                      \
                    asm volatile("" ::: "memory"); } while (0)
#define RBAR() do { asm volatile("" ::: "memory");                     \
                    __builtin_amdgcn_s_barrier();                      \
                    asm volatile("" ::: "memory"); } while (0)

// ---------------- tap helpers ---------------------------------------------
__device__ __forceinline__ void tap_load(const float* __restrict__ xg, int b, int irow,
                                         int jbase, int j, float v[8])
{
    int tpx = j & 63, cls = j >> 6;
    const float* cbase = xg + (b * 32 + cls) * 16384;
    #pragma unroll
    for (int t = 0; t < 8; ++t) {
        int di = (int)((0x22211000u >> (4 * t)) & 0xFu) - 1;
        int dj = (int)((0x21020210u >> (4 * t)) & 0xFu) - 1;
        int row = irow + di;
        int cc  = jbase + tpx + dj;
        bool okb = ((unsigned)row < 128u) && ((unsigned)cc < 128u);
        int off = okb ? (row * 128 + cc) : 0;      // clamped: always-safe load
        float x = cbase[off];
        v[t] = okb ? x : 0.0f;
    }
}

__device__ __forceinline__ void tap_write(U16* sL, int j, const float v[8])
{
    int tpx = j & 63, cls = j >> 6;
    bf16x8 T1, T2, T3; split3x8(v, T1, T2, T3);
    int to = tpx * 136 + 32 + cls * 8;
    *(bf16x8*)&sL[to] = T1;
    *(bf16x8*)&sL[8704 + to] = T2;
    *(bf16x8*)&sL[17408 + to] = T3;
}

// issue all global reads for one tile into registers
__device__ __forceinline__ void load_tile(const float* __restrict__ xg, int b, int irow,
                                          int jbase, int tid, int px, int cg,
                                          int wv, int quad, int col,
                                          float va[8], float vt0[8], float vt1[8],
                                          float vt2[8], float xs[2][4])
{
    const float* src = xg + (b * 32 + cg * 8) * 16384 + irow * 128 + jbase + px;
    #pragma unroll
    for (int i = 0; i < 8; ++i) va[i] = src[i * 16384];   // coalesced
    tap_load(xg, b, irow, jbase, tid,       vt0);
    tap_load(xg, b, irow, jbase, tid + 256, vt1);
    if (tid < 128) tap_load(xg, b, irow, jbase, tid + 512, vt2);
    // residual x: channel = n2*16+quad*4+r, pixel = wv*16+col (swapped layout)
    #pragma unroll
    for (int n2 = 0; n2 < 2; ++n2)
        #pragma unroll
        for (int r = 0; r < 4; ++r)
            xs[n2][r] = xg[(b * 32 + n2 * 16 + quad * 4 + r) * 16384
                           + irow * 128 + jbase + wv * 16 + col];
}

// split staged register values into the 3 LDS limb planes
__device__ __forceinline__ void stage_all(U16* sL, int tid, int px, int cg,
                                          const float va[8], const float vt0[8],
                                          const float vt1[8], const float vt2[8])
{
    {
        bf16x8 L1, L2, L3; split3x8(va, L1, L2, L3);
        int o = px * 136 + cg * 8;
        *(bf16x8*)&sL[o] = L1;
        *(bf16x8*)&sL[8704 + o] = L2;
        *(bf16x8*)&sL[17408 + o] = L3;
    }
    tap_write(sL, tid,       vt0);
    tap_write(sL, tid + 256, vt1);
    if (tid < 128) tap_write(sL, tid + 512, vt2);
    if (tid < 128) {                                  // zero pad k=112..127
        int zo = (tid >> 1) * 136 + 112 + (tid & 1) * 8;
        uint4 z = make_uint4(0u, 0u, 0u, 0u);
        *(uint4*)&sL[zo] = z;
        *(uint4*)&sL[8704 + zo] = z;
        *(uint4*)&sL[17408 + zo] = z;
    }
}

// ---- weight fragment group loads (unchanged addressing from r4) ----------
#define LDW1(g, ks_) do {                                                    \
    _Pragma("unroll") for (int L_ = 0; L_ < 3; ++L_)                         \
    _Pragma("unroll") for (int n_ = 0; n_ < 2; ++n_)                         \
        g[L_ * 2 + n_] = *(const bf16x8*)(w1p + L_ * 16384 + n_ * 2048 + (ks_) * 32); \
} while (0)

#define LDW2(q, ks_) do {                                                    \
    _Pragma("unroll") for (int L_ = 0; L_ < 3; ++L_)                         \
    _Pragma("unroll") for (int n_ = 0; n_ < 2; ++n_)                         \
        q[L_ * 2 + n_] = *(const bf16x8*)(w2p + L_ * 4096 + n_ * 2048 + (ks_) * 32); \
} while (0)

// ---- SWAPPED-operand MFMA clusters: mfma(W, P) = transpose of mfma(P, W) --
// identical scalar products in identical order -> bit-identical values;
// lane now holds (4 consecutive channels) x (1 pixel) -> vector h/dxl writes.
#define MFMA1S(ks_, g) do {                                                  \
    _Pragma("unroll") for (int mt_ = 0; mt_ < 4; ++mt_) {                    \
        const int ao_ = (mt_ * 16 + col) * 136 + (ks_) * 32 + quad * 8;      \
        bf16x8 A1_ = *(const bf16x8*)&sL[ao_];                               \
        bf16x8 A2_ = *(const bf16x8*)&sL[8704 + ao_];                        \
        bf16x8 A3_ = *(const bf16x8*)&sL[17408 + ao_];                       \
        _Pragma("unroll") for (int n_ = 0; n_ < 2; ++n_) {                   \
            f32x4 a_ = acc1[mt_][n_];                                        \
            a_ = __builtin_amdgcn_mfma_f32_16x16x32_bf16(g[0 + n_], A1_, a_, 0, 0, 0); \
            a_ = __builtin_amdgcn_mfma_f32_16x16x32_bf16(g[2 + n_], A1_, a_, 0, 0, 0); \
            a_ = __builtin_amdgcn_mfma_f32_16x16x32_bf16(g[0 + n_], A2_, a_, 0, 0, 0); \
            a_ = __builtin_amdgcn_mfma_f32_16x16x32_bf16(g[4 + n_], A1_, a_, 0, 0, 0); \
            a_ = __builtin_amdgcn_mfma_f32_16x16x32_bf16(g[2 + n_], A2_, a_, 0, 0, 0); \
            a_ = __builtin_amdgcn_mfma_f32_16x16x32_bf16(g[0 + n_], A3_, a_, 0, 0, 0); \
            acc1[mt_][n_] = a_;                                              \
        }                                                                    \
    }                                                                        \
} while (0)

#define MFMA2S(ks_, q) do {                                                  \
    const int ho_ = (wv * 16 + col) * 136 + (ks_) * 32 + quad * 8;           \
    bf16x8 H1_ = *(const bf16x8*)&sL[ho_];                                   \
    bf16x8 H2_ = *(const bf16x8*)&sL[8704 + ho_];                            \
    bf16x8 H3_ = *(const bf16x8*)&sL[17408 + ho_];                           \
    _Pragma("unroll") for (int n_ = 0; n_ < 2; ++n_) {                       \
        f32x4 a_ = acc2[n_];                                                 \
        a_ = __builtin_amdgcn_mfma_f32_16x16x32_bf16(q[0 + n_], H1_, a_, 0, 0, 0); \
        a_ = __builtin_amdgcn_mfma_f32_16x16x32_bf16(q[2 + n_], H1_, a_, 0, 0, 0); \
        a_ = __builtin_amdgcn_mfma_f32_16x16x32_bf16(q[0 + n_], H2_, a_, 0, 0, 0); \
        a_ = __builtin_amdgcn_mfma_f32_16x16x32_bf16(q[4 + n_], H1_, a_, 0, 0, 0); \
        a_ = __builtin_amdgcn_mfma_f32_16x16x32_bf16(q[2 + n_], H2_, a_, 0, 0, 0); \
        a_ = __builtin_amdgcn_mfma_f32_16x16x32_bf16(q[0 + n_], H3_, a_, 0, 0, 0); \
        acc2[n_] = a_;                                                       \
    }                                                                        \
} while (0)

// ---- streaming 3-pass epilogue (wave 0): bit-identical scalar op order ----
#define EPI3(jb_) do {                                                       \
    const float* dxr_ = (const float*)sL;                                    \
    int p_ = tid;                                                            \
    f32x4 e0_ = *(const f32x4*)&dxr_[p_ * 36 + 0];                           \
    f32x4 e1_ = *(const f32x4*)&dxr_[p_ * 36 + 4];                           \
    f32x4 e2_ = *(const f32x4*)&dxr_[p_ * 36 + 8];                           \
    float m_ = e0_[1];                                                       \
    m_ = fmaxf(m_, e0_[2]); m_ = fmaxf(m_, e0_[3]);                          \
    m_ = fmaxf(m_, e1_[0]); m_ = fmaxf(m_, e1_[1]);                          \
    m_ = fmaxf(m_, e1_[2]); m_ = fmaxf(m_, e1_[3]);                          \
    m_ = fmaxf(m_, e2_[0]); m_ = fmaxf(m_, e2_[1]);                          \
    float keep_ = (m_ > e0_[0]) ? 1.0f : 0.0f;                               \
    float s_ = 0.f;                                                          \
    s_ += e0_[0]; s_ += e0_[1]; s_ += e0_[2]; s_ += e0_[3];                  \
    s_ += e1_[0]; s_ += e1_[1]; s_ += e1_[2]; s_ += e1_[3];                  \
    s_ += e2_[0]; s_ += e2_[1];                                              \
    s_ += e2_[2] * keep_; s_ += e2_[3] * keep_;                              \
    _Pragma("unroll")                                                        \
    for (int i_ = 3; i_ < 8; ++i_) {                                         \
        f32x4 v_ = *(const f32x4*)&dxr_[p_ * 36 + i_ * 4];                   \
        s_ += v_[0] * keep_; s_ += v_[1] * keep_;                            \
        s_ += v_[2] * keep_; s_ += v_[3] * keep_;                            \
    }                                                                        \
    float mu_ = s_ * 0.03125f;                                               \
    float var_ = 0.f;                                                        \
    _Pragma("unroll")                                                        \
    for (int i_ = 0; i_ < 8; ++i_) {                                         \
        f32x4 v_ = *(const f32x4*)&dxr_[p_ * 36 + i_ * 4];                   \
        _Pragma("unroll")                                                    \
        for (int j_ = 0; j_ < 4; ++j_) {                                     \
            int c_ = i_ * 4 + j_;                                            \
            float x_ = (c_ >= 10) ? v_[j_] * keep_ : v_[j_];                 \
            float d_ = x_ - mu_; var_ += d_ * d_;                            \
        }                                                                    \
    }                                                                        \
    var_ *= 0.03125f;                                                        \
    float rstd_ = 1.0f / sqrtf(var_ + 1e-5f);                                \
    int base_ = b * 524288 + irow * 128 + (jb_) + p_;                        \
    _Pragma("unroll")                                                        \
    for (int i_ = 0; i_ < 8; ++i_) {                                         \
        f32x4 v_ = *(const f32x4*)&dxr_[p_ * 36 + i_ * 4];                   \
        _Pragma("unroll")                                                    \
        for (int j_ = 0; j_ < 4; ++j_) {                                     \
            int c_ = i_ * 4 + j_;                                            \
            float x_ = (c_ >= 10) ? v_[j_] * keep_ : v_[j_];                 \
            outg[base_ + c_ * 16384] = (x_ - mu_) * rstd_ * gg[c_] + bg[c_]; \
        }                                                                    \
    }                                                                        \
} while (0)

// one full tile: stage -> stage1 -> h -> stage2 -> dxl -> epilogue.
// PRE_: issue next tile's global loads after B3 (hidden under stage2+epilogue)
#define TILE_BODY(jb_, XS_, PRE_, jb2_, XSN_) do {                           \
    stage_all(sL, tid, px, cg, va, vt0, vt1, vt2);                           \
    bf16x8 g0[6], g1[6], g2[6], g3[6];                                       \
    LDW1(g0, 0); LDW1(g1, 1);                                                \
    WBAR();   /* B1: perc planes published, prefetches in flight */          \
    f32x4 acc1[4][2];                                                        \
    _Pragma("unroll")                                                        \
    for (int mt_ = 0; mt_ < 4; ++mt_) { acc1[mt_][0] = fz; acc1[mt_][1] = fz; } \
    LDW1(g2, 2);                                                             \
    __builtin_amdgcn_sched_group_barrier(0x20, 6, 0);                        \
    MFMA1S(0, g0);                                                           \
    LDW1(g3, 3);                                                             \
    __builtin_amdgcn_sched_group_barrier(0x20, 6, 0);                        \
    MFMA1S(1, g1);                                                           \
    MFMA1S(2, g2);                                                           \
    MFMA1S(3, g3);                                                           \
    RBAR();   /* B2: perc reads consumed -> planes reusable for h */         \
    bf16x8 q0[6], q1[6], q2[6], q3[6];                                       \
    LDW2(q0, 0); LDW2(q1, 1);                                                \
    __builtin_amdgcn_sched_group_barrier(0x20, 12, 0);                       \
    /* h -> 3 limb planes; lane holds 4 consecutive channels -> b64 writes */ \
    _Pragma("unroll")                                                        \
    for (int mt_ = 0; mt_ < 4; ++mt_)                                        \
        _Pragma("unroll")                                                    \
        for (int n_ = 0; n_ < 2; ++n_) {                                     \
            u16x4 o1_, o2_, o3_;                                             \
            _Pragma("unroll")                                                \
            for (int r_ = 0; r_ < 4; ++r_) {                                 \
                float v_ = fmaxf(acc1[mt_][n_][r_] + b1v[n_][r_], 0.0f);     \
                U16 u1_, u2_, u3_; split3(v_, u1_, u2_, u3_);                \
                o1_[r_] = u1_; o2_[r_] = u2_; o3_[r_] = u3_;                 \
            }                                                                \
            int ho_ = (mt_ * 16 + col) * 136 + wv * 32 + n_ * 16 + quad * 4; \
            *(u16x4*)&sL[ho_] = o1_;                                         \
            *(u16x4*)&sL[8704 + ho_] = o2_;                                  \
            *(u16x4*)&sL[17408 + ho_] = o3_;                                 \
        }                                                                    \
    WBAR();   /* B3: h planes published */                                   \
    if (PRE_) load_tile(xg, b, irow, (jb2_), tid, px, cg, wv, quad, col,     \
                        va, vt0, vt1, vt2, XSN_);                            \
    f32x4 acc2[2];                                                           \
    acc2[0] = fz; acc2[1] = fz;                                              \
    LDW2(q2, 2);                                                             \
    __builtin_amdgcn_sched_group_barrier(0x20, 6, 0);                        \
    MFMA2S(0, q0);                                                           \
    LDW2(q3, 3);                                                             \
    __builtin_amdgcn_sched_group_barrier(0x20, 6, 0);                        \
    MFMA2S(1, q1);                                                           \
    MFMA2S(2, q2);                                                           \
    MFMA2S(3, q3);                                                           \
    RBAR();   /* B4a: stage-2 h reads consumed -> plane mem reusable */      \
    {   /* new_state = dx + b2 + x -> dxl f32 [64][36], vector writes */     \
        float* dxl_ = (float*)sL;                                            \
        _Pragma("unroll")                                                    \
        for (int n_ = 0; n_ < 2; ++n_) {                                     \
            f32x4 vv_;                                                       \
            _Pragma("unroll")                                                \
            for (int r_ = 0; r_ < 4; ++r_)                                   \
                vv_[r_] = acc2[n_][r_] + b2v[n_][r_] + XS_[n_][r_];          \
            *(f32x4*)&dxl_[(wv * 16 + col) * 36 + n_ * 16 + quad * 4] = vv_; \
        }                                                                    \
    }                                                                        \
    WBAR();   /* B4: new_state complete */                                   \
    if (tid < 64) EPI3(jb_);                                                 \
    if (PRE_) WBAR();  /* B5: wave0 dxl reads drained before next staging */ \
} while (0)

// ---------------- main ----------------------------------------------------
// B=64, C=32, H=W=128. Block = 256 thr = 4 waves; TWO tiles per block (one
// full row: jseg 0 then 1). Tile-B global loads issue under tile-A's stage-2
// + epilogue (raw barriers never drain vmcnt). Swapped-operand MFMAs give
// vectorized h (b64) and dxl (b128) writes. Output bit-identical to r4.
__global__ __launch_bounds__(256, 3)
void cann_kernel(const float* __restrict__ xg,  const U16* __restrict__ w1L,
                 const U16* __restrict__ w2L,
                 const float* __restrict__ b1g, const float* __restrict__ b2g,
                 const float* __restrict__ gg,  const float* __restrict__ bg,
                 float* __restrict__ outg)
{
    __shared__ __align__(16) U16 sL[3 * 8704];        // 52224 B -> 3 blocks/CU

    const int tid  = threadIdx.x;
    const int bid0 = blockIdx.x;
    const int bid  = (bid0 & 7) * 1024 + (bid0 >> 3); // XCD-contiguous, bijective
    const int irow = bid & 127;
    const int b    = bid >> 7;
    const int lane = tid & 63;
    const int wv   = tid >> 6;
    const int quad = lane >> 4;
    const int col  = lane & 15;
    const int px   = tid & 63;
    const int cg   = tid >> 6;

    const U16* w1p = w1L + (wv * 32 + col) * 128 + quad * 8;
    const U16* w2p = w2L + col * 128 + quad * 8;

    // per-lane params (swapped layout: lane owns channels n2*16+quad*4+r)
    float b1v[2][4], b2v[2][4];
    #pragma unroll
    for (int n2 = 0; n2 < 2; ++n2)
        #pragma unroll
        for (int r = 0; r < 4; ++r) {
            b1v[n2][r] = b1g[wv * 32 + n2 * 16 + quad * 4 + r];
            b2v[n2][r] = b2g[n2 * 16 + quad * 4 + r];
        }

    const f32x4 fz = {0.f, 0.f, 0.f, 0.f};

    float va[8], vt0[8], vt1[8], vt2[8], xsA[2][4], xsB[2][4];
    load_tile(xg, b, irow, 0, tid, px, cg, wv, quad, col, va, vt0, vt1, vt2, xsA);

    TILE_BODY(0,  xsA, 1, 64, xsB);    // tile A (jseg 0), prefetch tile B
    TILE_BODY(64, xsB, 0, 0,  xsA);    // tile B (jseg 1)
}

extern "C" void kernel_launch(void* const* d_in, const int* in_sizes, int n_in,
                              void* d_out, int out_size, void* d_ws, size_t ws_size,
                              hipStream_t stream) {
    const float* x  = (const float*)d_in[0];
    const float* w1 = (const float*)d_in[1];
    const float* b1 = (const float*)d_in[2];
    const float* w2 = (const float*)d_in[3];
    const float* b2 = (const float*)d_in[4];
    const float* g  = (const float*)d_in[5];
    const float* be = (const float*)d_in[6];
    float* out = (float*)d_out;

    U16* w1L = (U16*)d_ws;                       // 98304 B
    U16* w2L = (U16*)((char*)d_ws + 98304);      // 24576 B (total 122880 <= ws)

    hipLaunchKernelGGL(prep_kernel, dim3(8), dim3(256), 0, stream, w1, w2, w1L, w2L);
    // grid: 64 (B) * 128 (rows) = 8192 blocks, 2 tiles (row halves) each
    hipLaunchKernelGGL(cann_kernel, dim3(8192), dim3(256), 0, stream,
                       x, w1L, w2L, b1, b2, g, be, out);
}